// Round 6
// baseline (131.230 us; speedup 1.0000x reference)
//
#include <hip/hip_runtime.h>
#include <hip/hip_bf16.h>

// CondLaneHead via bf16 MFMA 16x16x32, 3 layers fused.
// 32 instances (4 img x 8), C=64, H=160, W=256, L=40960 px.
//
// Round-5 lesson: per-wave weight-frag loads from L2 were 1.5 GB (~44 us at
// 34.5 TB/s) -- the real bottleneck. This round: (a) weights staged to LDS
// once per block (dbuf, cooperative copy) -- kills 4x wave redundancy;
// (b) b0/wx/wy/b1/w2 kept as raw 64-float vectors (broadcast ds_read_b128,
// not 16x-replicated D-frags); (c) 256 px/block halves weight traffic per
// pixel; (d) h C->B transform via shfl (ds_bpermute), no LDS h buffer.
//
// Frag layouts (m89/m120-verified): A[m=lane&15][k=(lane>>4)*8+j],
// B[k=(lane>>4)*8+j][n=lane&15], D[row=(lane>>4)*4+r][col=lane&15].
//
// ws per instance (20480 B): [0,8192) w0 A-frags (frag f: f*1024+lane*16),
// [8192,16384) w1 A-frags, [16384,+4096) vec: b0[64] wx[64] wy[64] b1[64]
// w2[64] b2 pad. Block = one image row (W=256), so fy is block-constant.

#define NP 8513
#define HW 40960
#define WSI 20480

typedef __attribute__((ext_vector_type(8))) short bf16x8;
typedef __attribute__((ext_vector_type(4))) float f32x4;

__device__ inline unsigned short f2bf(float f) {
  union { float f; unsigned u; } v; v.f = f;
  unsigned r = v.u + 0x7fffu + ((v.u >> 16) & 1u);   // RNE
  return (unsigned short)(r >> 16);
}
__device__ inline unsigned pk2(float a, float b) {   // [lo=a, hi=b] bf16x2
  __hip_bfloat162 h = __float22bfloat162_rn(float2{a, b});
  union { __hip_bfloat162 h; unsigned u; } v; v.h = h;
  return v.u;
}

__global__ void condlane_prep(const float* __restrict__ params,
                              char* __restrict__ ws) {
  const int inst = blockIdx.x >> 3, part = blockIdx.x & 7;
  const float* __restrict__ p = params + inst * NP;
  char* base = ws + inst * WSI;
  const int t = threadIdx.x;
  if (part < 2) {            // w0 A-frags
    unsigned short* dst = (unsigned short*)base;
#pragma unroll
    for (int it = 0; it < 8; it++) {
      const int e = part * 2048 + it * 256 + t;
      const int frag = e >> 9, lane = (e >> 3) & 63, j = e & 7;
      const int m = (frag >> 1) * 16 + (lane & 15);
      const int k = (frag & 1) * 32 + ((lane >> 4) << 3) + j;
      dst[e] = f2bf(p[m * 66 + 2 + k]);
    }
  } else if (part < 4) {     // w1 A-frags
    unsigned short* dst = (unsigned short*)(base + 8192);
#pragma unroll
    for (int it = 0; it < 8; it++) {
      const int e = (part - 2) * 2048 + it * 256 + t;
      const int frag = e >> 9, lane = (e >> 3) & 63, j = e & 7;
      const int m = (frag >> 1) * 16 + (lane & 15);
      const int k = (frag & 1) * 32 + ((lane >> 4) << 3) + j;
      dst[e] = f2bf(p[4224 + m * 64 + k]);
    }
  } else if (part == 4) {    // raw vectors + b2 (+ zero pad)
    float* vec = (float*)(base + 16384);
    if (t < 64) {
      vec[t]       = p[8384 + t];   // b0
      vec[64 + t]  = p[t * 66];     // wx
      vec[128 + t] = p[t * 66 + 1]; // wy
      vec[192 + t] = p[8448 + t];   // b1
      vec[256 + t] = p[8320 + t];   // w2
    } else if (t == 64) vec[320] = p[8512] - 2.19f;
    for (int e = 321 + t; e < 1024; e += 256) vec[e] = 0.f;
  }
}

__global__ __launch_bounds__(256, 2) void condlane_main(
    const float* __restrict__ x, const char* __restrict__ ws,
    float* __restrict__ out) {
  __shared__ __align__(16) unsigned short xs[256 * 64];  // 32 KB, swizzled
  __shared__ __align__(16) char wl[2][WSI];              // 40 KB weight dbuf
  const int img = blockIdx.y, bx = blockIdx.x;           // bx = image row y
  const int tid = threadIdx.x, lane = tid & 63, wave = tid >> 6;
  const int col = lane & 15, q = lane >> 4;

  // ---- stage x row (256 px): thread = one pixel, 64 channels ----
  {
    const float* gx = x + img * 64 * HW + bx * 256 + tid;
    unsigned short* row = xs + tid * 64;
    const int psw = tid & 7;
#pragma unroll
    for (int cb = 0; cb < 8; cb++) {
      union { bf16x8 v; unsigned short s[8]; } u;
#pragma unroll
      for (int j = 0; j < 8; j++) u.s[j] = f2bf(gx[(cb * 8 + j) * HW]);
      *(bf16x8*)(row + ((cb ^ psw) << 3)) = u.v;
    }
  }
  // ---- stage instance-0 weights: global -> regs -> LDS buf0 ----
  const char* wsi = ws + img * 8 * WSI;
  {
    uint4 st[5];
#pragma unroll
    for (int j = 0; j < 5; j++)
      st[j] = *(const uint4*)(wsi + j * 4096 + tid * 16);
#pragma unroll
    for (int j = 0; j < 5; j++)
      *(uint4*)(wl[0] + j * 4096 + tid * 16) = st[j];
  }
  __syncthreads();

  // x B-frags to regs once; reused across all 8 instances
  bf16x8 bfr[4][2];
#pragma unroll
  for (int nt = 0; nt < 4; nt++)
#pragma unroll
    for (int ks = 0; ks < 2; ks++) {
      const int row = wave * 64 + nt * 16 + col;
      bfr[nt][ks] = *(const bf16x8*)(xs + row * 64 +
                                     (((ks * 4 + q) ^ (row & 7)) << 3));
    }
  const float fyv = (float)bx;
  float fxv[4];
#pragma unroll
  for (int nt = 0; nt < 4; nt++) fxv[nt] = (float)(wave * 64 + nt * 16 + col);

  const int srcA = ((lane >> 4) & 1) * 32 + col;   // source lanes for h shfl
  const int srcB = srcA + 16;
  const bool lowq = q < 2;
  float* outb = out + img * 8 * HW + bx * 256 + wave * 64 + lane;

  for (int i = 0; i < 8; i++) {
    // prefetch next instance's weights to regs (coalesced; overlaps compute)
    uint4 st[5];
    if (i < 7) {
#pragma unroll
      for (int j = 0; j < 5; j++)
        st[j] = *(const uint4*)(wsi + (i + 1) * WSI + j * 4096 + tid * 16);
    }
    const char* lb = wl[i & 1];
    const unsigned short* w0f = (const unsigned short*)lb;
    const unsigned short* w1f = (const unsigned short*)(lb + 8192);
    const float* vec = (const float*)(lb + 16384);

    // ---- layer 1: C-init = b0 + wy*fy + wx*fx (exact fp32), K=64 MFMA ----
    f32x4 acc[4][4];
#pragma unroll
    for (int mt = 0; mt < 4; mt++) {
      const int ro = mt * 16 + q * 4;
      const f32x4 b0v = *(const f32x4*)(vec + ro);          // broadcast reads
      const f32x4 wxv = *(const f32x4*)(vec + 64 + ro);
      const f32x4 wyv = *(const f32x4*)(vec + 128 + ro);
      const f32x4 byv = b0v + wyv * fyv;
#pragma unroll
      for (int nt = 0; nt < 4; nt++) acc[mt][nt] = byv + wxv * fxv[nt];
    }
#pragma unroll
    for (int mt = 0; mt < 4; mt++) {
      const bf16x8 a0 = *(const bf16x8*)(w0f + (mt * 2 + 0) * 512 + lane * 8);
      const bf16x8 a1 = *(const bf16x8*)(w0f + (mt * 2 + 1) * 512 + lane * 8);
#pragma unroll
      for (int nt = 0; nt < 4; nt++) {
        f32x4 c = __builtin_amdgcn_mfma_f32_16x16x32_bf16(a0, bfr[nt][0],
                                                          acc[mt][nt], 0, 0, 0);
        acc[mt][nt] = __builtin_amdgcn_mfma_f32_16x16x32_bf16(a1, bfr[nt][1],
                                                              c, 0, 0, 0);
      }
    }
    // ---- relu + pack to bf16x2 dwords ----
    unsigned pk0[4][4], pk1[4][4];
#pragma unroll
    for (int mt = 0; mt < 4; mt++)
#pragma unroll
      for (int nt = 0; nt < 4; nt++) {
        const f32x4 v = acc[mt][nt];
        pk0[mt][nt] = pk2(fmaxf(v.x, 0.f), fmaxf(v.y, 0.f));
        pk1[mt][nt] = pk2(fmaxf(v.z, 0.f), fmaxf(v.w, 0.f));
      }
    // ---- D-layout -> B-frag transform via shfl (no LDS) ----
    // dest lane (q,col) needs rows (q&1)*8..+7 of tile mt=2ks+(q>>1),
    // held by lanes srcA=((q&1)*2)*16+col (r0..3) and srcB=srcA+16 (r4..7).
    bf16x8 hbf[4][2];
#pragma unroll
    for (int nt = 0; nt < 4; nt++)
#pragma unroll
      for (int ks = 0; ks < 2; ks++) {
        const int mA = 2 * ks, mB = 2 * ks + 1;
        const unsigned tA0 = __shfl((int)pk0[mA][nt], srcA, 64);
        const unsigned tA1 = __shfl((int)pk1[mA][nt], srcA, 64);
        const unsigned tA2 = __shfl((int)pk0[mA][nt], srcB, 64);
        const unsigned tA3 = __shfl((int)pk1[mA][nt], srcB, 64);
        const unsigned tB0 = __shfl((int)pk0[mB][nt], srcA, 64);
        const unsigned tB1 = __shfl((int)pk1[mB][nt], srcA, 64);
        const unsigned tB2 = __shfl((int)pk0[mB][nt], srcB, 64);
        const unsigned tB3 = __shfl((int)pk1[mB][nt], srcB, 64);
        union { bf16x8 v; unsigned d[4]; } u;
        u.d[0] = lowq ? tA0 : tB0;
        u.d[1] = lowq ? tA1 : tB1;
        u.d[2] = lowq ? tA2 : tB2;
        u.d[3] = lowq ? tA3 : tB3;
        hbf[nt][ks] = u.v;
      }
    // ---- layer 2 (C=b1) + layer 3 dot(w2, relu) fused per mt ----
    float s[4] = {0.f, 0.f, 0.f, 0.f};
#pragma unroll
    for (int mt = 0; mt < 4; mt++) {
      const int ro = mt * 16 + q * 4;
      const f32x4 cb  = *(const f32x4*)(vec + 192 + ro);
      const f32x4 w2v = *(const f32x4*)(vec + 256 + ro);
      const bf16x8 a0 = *(const bf16x8*)(w1f + (mt * 2 + 0) * 512 + lane * 8);
      const bf16x8 a1 = *(const bf16x8*)(w1f + (mt * 2 + 1) * 512 + lane * 8);
#pragma unroll
      for (int nt = 0; nt < 4; nt++) {
        f32x4 c = __builtin_amdgcn_mfma_f32_16x16x32_bf16(a0, hbf[nt][0],
                                                          cb, 0, 0, 0);
        const f32x4 v = __builtin_amdgcn_mfma_f32_16x16x32_bf16(a1, hbf[nt][1],
                                                                c, 0, 0, 0);
        s[nt] += w2v.x * fmaxf(v.x, 0.f) + w2v.y * fmaxf(v.y, 0.f) +
                 w2v.z * fmaxf(v.z, 0.f) + w2v.w * fmaxf(v.w, 0.f);
      }
    }
    const float b2 = vec[320];
#pragma unroll
    for (int nt = 0; nt < 4; nt++) {
      s[nt] += __shfl_xor(s[nt], 16, 64);
      s[nt] += __shfl_xor(s[nt], 32, 64);
    }
    const float sel = (q == 0) ? s[0] : (q == 1) ? s[1] : (q == 2) ? s[2] : s[3];
    outb[i * HW] = sel + b2;                 // 64 contiguous px per wave

    // write prefetched weights into the other buffer, then barrier
    if (i < 7) {
      char* nb = wl[(i + 1) & 1];
#pragma unroll
      for (int j = 0; j < 5; j++)
        *(uint4*)(nb + j * 4096 + tid * 16) = st[j];
      __syncthreads();
    }
  }
}

extern "C" void kernel_launch(void* const* d_in, const int* in_sizes, int n_in,
                              void* d_out, int out_size, void* d_ws, size_t ws_size,
                              hipStream_t stream) {
  const float* x      = (const float*)d_in[0];  // [4,64,160,256] fp32
  const float* params = (const float*)d_in[1];  // [32,8513] fp32
  // d_in[2] = num_ins (static 8/img; inst mapping hardcoded)
  float* out = (float*)d_out;

  condlane_prep<<<256, 256, 0, stream>>>(params, (char*)d_ws);  // 655 KB used
  condlane_main<<<dim3(160, 4), 256, 0, stream>>>(x, (const char*)d_ws, out);
}